// Round 1
// baseline (467.872 us; speedup 1.0000x reference)
//
#include <hip/hip_runtime.h>
#include <hip/hip_bf16.h>
#include <cstdint>
#include <cstddef>

#define MSETS 4096
#define SET_SZ 1024
#define NBINS 128
#define DMODEL 1024
#define DPHI 512
#define WIN 48

// ---------------------------------------------------------------- counts ----
__global__ void counts_kernel(const int* __restrict__ token_ids,
                              const int* __restrict__ set_indices,
                              const int* __restrict__ set_sizes,
                              float* __restrict__ counts) {
    __shared__ int hist[NBINS];
    int m = blockIdx.x;
    for (int t = threadIdx.x; t < NBINS; t += blockDim.x) hist[t] = 0;
    __syncthreads();
    const int* row = set_indices + (size_t)m * SET_SZ;
    for (int s = threadIdx.x; s < SET_SZ; s += blockDim.x) {
        int idx = row[s];
        if (idx >= 0) {
            int tok = token_ids[idx];
            int bin = ((tok & 127) * 39 + 13) & 127;   // (tok%128)*(MULT%128)+13 mod 128
            atomicAdd(&hist[bin], 1);
        }
    }
    __syncthreads();
    float denom = fmaxf((float)set_sizes[m], 1.0f);
    for (int t = threadIdx.x; t < NBINS; t += blockDim.x)
        counts[(size_t)m * NBINS + t] = (float)hist[t] / denom;
}

// ------------------------------------------------------------- geom_bias ----
__global__ void geom_bias_kernel(const float* __restrict__ pos,
                                 float* __restrict__ out2) {
    __shared__ float sp[MSETS];
    for (int j = threadIdx.x; j < MSETS; j += blockDim.x) sp[j] = pos[j];
    __syncthreads();
    int i = blockIdx.x;
    float pi = sp[i];
    float4* row = (float4*)(out2 + (size_t)i * MSETS);
    const float4* sp4 = (const float4*)sp;
    for (int j4 = threadIdx.x; j4 < MSETS / 4; j4 += blockDim.x) {
        float4 p = sp4[j4];
        float4 v;
        v.x = -fabsf(pi - p.x);
        v.y = -fabsf(pi - p.y);
        v.z = -fabsf(pi - p.z);
        v.w = -fabsf(pi - p.w);
        row[j4] = v;
    }
}

// ---------------------------------------------------- proj_geom (banded) ----
// proj_geom[i,p] = geom_b[p] + sum_j exp(-|i-j|) * geom_w[p,j]; terms beyond
// |i-j|>WIN are < 1e-21 relative -> negligible vs fp32 and 2% threshold.
__global__ void projgeom_kernel(const float* __restrict__ geom_w,
                                const float* __restrict__ geom_b,
                                float* __restrict__ fused) {
    __shared__ float row[MSETS];
    __shared__ float wt[WIN + 1];
    int p = blockIdx.x;
    const float* gw = geom_w + (size_t)p * MSETS;
    for (int j = threadIdx.x; j < MSETS; j += blockDim.x) row[j] = gw[j];
    if (threadIdx.x <= WIN) wt[threadIdx.x] = expf(-(float)threadIdx.x);
    __syncthreads();
    float gb = geom_b[p];
    for (int i = threadIdx.x; i < MSETS; i += blockDim.x) {
        float acc = row[i];
        for (int d = 1; d <= WIN; ++d) {
            float s = 0.0f;
            int lo = i - d, hi = i + d;
            if (lo >= 0) s += row[lo];
            if (hi < MSETS) s += row[hi];
            acc = fmaf(wt[d], s, acc);
        }
        fused[(size_t)i * (2 * DPHI) + p] = acc + gb;
    }
}

// ---------------------------------------------------------------- b2 ---------
// b2[n] = rf_b[n] + sum_j rc_b[j] * rf_w[n, 1024+j]
__global__ void b2_kernel(const float* __restrict__ rf_w,
                          const float* __restrict__ rf_b,
                          const float* __restrict__ rc_b,
                          float* __restrict__ b2) {
    int n = blockIdx.x * blockDim.x + threadIdx.x;
    if (n >= DMODEL) return;
    const float* row = rf_w + (size_t)n * (2 * DMODEL) + DMODEL;
    float acc = rf_b[n];
    for (int j = 0; j < DMODEL; ++j) acc = fmaf(rc_b[j], row[j], acc);
    b2[n] = acc;
}

// ------------------------------------------------------------ fp32 GEMM ------
__device__ inline float gelu_exact(float x) {
    return 0.5f * x * (1.0f + erff(x * 0.70710678118654752f));
}

// C[M,N] = A[M,K] @ op(B) (+bias) (+C if ACCUM) (gelu if ACT)
// BT=true: B is [N,K] row-major (X @ W.T). BT=false: B is [K,N] row-major.
// All of M,N multiples of 64; K multiple of 16. Tile 64x64, 256 threads.
template<int ACT, bool ACCUM, bool BT>
__global__ __launch_bounds__(256) void gemm64(const float* __restrict__ A, int lda,
                                              const float* __restrict__ B, int ldb,
                                              float* __restrict__ C, int ldc,
                                              const float* __restrict__ bias, int K) {
    __shared__ float As[16][68];
    __shared__ float Bs[16][68];
    const int tid = threadIdx.x;
    const int tx = tid & 15, ty = tid >> 4;
    const int i0 = blockIdx.y * 64, j0 = blockIdx.x * 64;
    const int arow = tid >> 2, akq = (tid & 3) * 4;
    float acc[4][4] = {};

    for (int k0 = 0; k0 < K; k0 += 16) {
        float4 a4 = *(const float4*)(A + (size_t)(i0 + arow) * lda + k0 + akq);
        As[akq + 0][arow] = a4.x;
        As[akq + 1][arow] = a4.y;
        As[akq + 2][arow] = a4.z;
        As[akq + 3][arow] = a4.w;
        if (BT) {
            float4 b4 = *(const float4*)(B + (size_t)(j0 + arow) * ldb + k0 + akq);
            Bs[akq + 0][arow] = b4.x;
            Bs[akq + 1][arow] = b4.y;
            Bs[akq + 2][arow] = b4.z;
            Bs[akq + 3][arow] = b4.w;
        } else {
            int bk = tid >> 4, bj = (tid & 15) * 4;
            float4 b4 = *(const float4*)(B + (size_t)(k0 + bk) * ldb + j0 + bj);
            *(float4*)&Bs[bk][bj] = b4;
        }
        __syncthreads();
#pragma unroll
        for (int kk = 0; kk < 16; ++kk) {
            float4 a = *(const float4*)&As[kk][ty * 4];
            float4 b = *(const float4*)&Bs[kk][tx * 4];
            float av[4] = {a.x, a.y, a.z, a.w};
            float bv[4] = {b.x, b.y, b.z, b.w};
#pragma unroll
            for (int r = 0; r < 4; ++r)
#pragma unroll
                for (int c = 0; c < 4; ++c)
                    acc[r][c] = fmaf(av[r], bv[c], acc[r][c]);
        }
        __syncthreads();
    }

#pragma unroll
    for (int r = 0; r < 4; ++r) {
        int i = i0 + ty * 4 + r;
        float4* crow = (float4*)(C + (size_t)i * ldc + j0 + tx * 4);
        float4 v = make_float4(acc[r][0], acc[r][1], acc[r][2], acc[r][3]);
        if (bias) {
            float4 bb = *(const float4*)(bias + j0 + tx * 4);
            v.x += bb.x; v.y += bb.y; v.z += bb.z; v.w += bb.w;
        }
        if (ACCUM) {
            float4 co = *crow;
            v.x += co.x; v.y += co.y; v.z += co.z; v.w += co.w;
        }
        if (ACT == 1) {
            v.x = gelu_exact(v.x);
            v.y = gelu_exact(v.y);
            v.z = gelu_exact(v.z);
            v.w = gelu_exact(v.w);
        }
        *crow = v;
    }
}

// ---------------------------------------------------------------- launch -----
extern "C" void kernel_launch(void* const* d_in, const int* in_sizes, int n_in,
                              void* d_out, int out_size, void* d_ws, size_t ws_size,
                              hipStream_t stream) {
    const int*   token_ids   = (const int*)d_in[0];
    const int*   set_indices = (const int*)d_in[1];
    const int*   set_sizes   = (const int*)d_in[2];
    const float* set_pos     = (const float*)d_in[3];
    const float* set_states  = (const float*)d_in[4];
    const float* geom_w      = (const float*)d_in[5];
    const float* geom_b      = (const float*)d_in[6];
    const float* count_w     = (const float*)d_in[7];
    const float* count_b     = (const float*)d_in[8];
    const float* rc_w        = (const float*)d_in[9];
    const float* rc_b        = (const float*)d_in[10];
    const float* rf_w        = (const float*)d_in[11];
    const float* rf_b        = (const float*)d_in[12];
    const float* f1_w        = (const float*)d_in[13];
    const float* f1_b        = (const float*)d_in[14];
    const float* f2_w        = (const float*)d_in[15];
    const float* f2_b        = (const float*)d_in[16];

    float* out_phi  = (float*)d_out;                                  // [4096,512]
    float* out_desc = out_phi + (size_t)MSETS * DPHI;                 // [4096,1024]
    float* out_gb   = out_desc + (size_t)MSETS * DMODEL;              // [4096,4096]

    float* ws     = (float*)d_ws;
    float* counts = ws;                                    // 4096*128
    float* fused  = counts + (size_t)MSETS * NBINS;        // 4096*1024
    float* hbuf   = fused + (size_t)MSETS * 2 * DPHI;      // 4096*512
    float* W2     = hbuf + (size_t)MSETS * DPHI;           // 1024*128
    float* b2     = W2 + (size_t)DMODEL * NBINS;           // 1024

    // independent pieces
    counts_kernel<<<MSETS, 256, 0, stream>>>(token_ids, set_indices, set_sizes, counts);
    geom_bias_kernel<<<MSETS, 256, 0, stream>>>(set_pos, out_gb);
    projgeom_kernel<<<DPHI, 256, 0, stream>>>(geom_w, geom_b, fused);

    // proj_counts -> fused[:, 512:1024]
    gemm64<0, false, true><<<dim3(DPHI / 64, MSETS / 64), 256, 0, stream>>>(
        counts, NBINS, count_w, NBINS, fused + DPHI, 2 * DPHI, count_b, NBINS);

    // fold: W2[1024,128] = rf_w[:,1024:2048] @ rc_w
    gemm64<0, false, false><<<dim3(NBINS / 64, DMODEL / 64), 256, 0, stream>>>(
        rf_w + DMODEL, 2 * DMODEL, rc_w, NBINS, W2, NBINS, nullptr, DMODEL);
    b2_kernel<<<(DMODEL + 255) / 256, 256, 0, stream>>>(rf_w, rf_b, rc_b, b2);

    // desc_router = counts @ W2.T + b2, then += set_states @ rf_w[:, :1024].T
    gemm64<0, false, true><<<dim3(DMODEL / 64, MSETS / 64), 256, 0, stream>>>(
        counts, NBINS, W2, NBINS, out_desc, DMODEL, b2, NBINS);
    gemm64<0, true, true><<<dim3(DMODEL / 64, MSETS / 64), 256, 0, stream>>>(
        set_states, DMODEL, rf_w, 2 * DMODEL, out_desc, DMODEL, nullptr, DMODEL);

    // h = gelu(fused @ f1_w.T + f1_b)
    gemm64<1, false, true><<<dim3(DPHI / 64, MSETS / 64), 256, 0, stream>>>(
        fused, 2 * DPHI, f1_w, 2 * DPHI, hbuf, DPHI, f1_b, 2 * DPHI);

    // phi_attn = h @ f2_w.T + f2_b
    gemm64<0, false, true><<<dim3(DPHI / 64, MSETS / 64), 256, 0, stream>>>(
        hbuf, DPHI, f2_w, DPHI, out_phi, DPHI, f2_b, DPHI);
}

// Round 2
// 336.329 us; speedup vs baseline: 1.3911x; 1.3911x over previous
//
#include <hip/hip_runtime.h>
#include <hip/hip_bf16.h>
#include <cstdint>
#include <cstddef>

#define MSETS 4096
#define SET_SZ 1024
#define NBINS 128
#define DMODEL 1024
#define DPHI 512
#define WIN 48

typedef float f32x4 __attribute__((ext_vector_type(4)));
typedef __bf16 bf16x8 __attribute__((ext_vector_type(8)));

__device__ inline float gelu_exact(float x) {
    return 0.5f * x * (1.0f + erff(x * 0.70710678118654752f));
}

// ---------------------------------------------------------------- counts ----
// histogram per set -> bf16 counts written into catA[:, 1024:1152]
__global__ void counts_kernel(const int* __restrict__ token_ids,
                              const int* __restrict__ set_indices,
                              const int* __restrict__ set_sizes,
                              __hip_bfloat16* __restrict__ catA) {
    __shared__ int hist[NBINS];
    int m = blockIdx.x;
    for (int t = threadIdx.x; t < NBINS; t += blockDim.x) hist[t] = 0;
    __syncthreads();
    const int* row = set_indices + (size_t)m * SET_SZ;
    for (int s = threadIdx.x; s < SET_SZ; s += blockDim.x) {
        int idx = row[s];
        if (idx >= 0) {
            int tok = token_ids[idx];
            int bin = ((tok & 127) * 39 + 13) & 127;
            atomicAdd(&hist[bin], 1);
        }
    }
    __syncthreads();
    float denom = fmaxf((float)set_sizes[m], 1.0f);
    for (int t = threadIdx.x; t < NBINS; t += blockDim.x)
        catA[(size_t)m * 1152 + 1024 + t] = __float2bfloat16((float)hist[t] / denom);
}

// ------------------------------------------------------------- geom_bias ----
__global__ void geom_bias_kernel(const float* __restrict__ pos,
                                 float* __restrict__ out2) {
    __shared__ float sp[MSETS];
    for (int j = threadIdx.x; j < MSETS; j += blockDim.x) sp[j] = pos[j];
    __syncthreads();
    int i = blockIdx.x;
    float pi = sp[i];
    float4* row = (float4*)(out2 + (size_t)i * MSETS);
    const float4* sp4 = (const float4*)sp;
    for (int j4 = threadIdx.x; j4 < MSETS / 4; j4 += blockDim.x) {
        float4 p = sp4[j4];
        float4 v;
        v.x = -fabsf(pi - p.x);
        v.y = -fabsf(pi - p.y);
        v.z = -fabsf(pi - p.z);
        v.w = -fabsf(pi - p.w);
        row[j4] = v;
    }
}

// ---------------------------------------------------- proj_geom (banded) ----
// exp(-|i-j|) decays below 1e-21 past WIN; writes bf16 into fusedb[:, 0:512]
__global__ void projgeom_kernel(const float* __restrict__ geom_w,
                                const float* __restrict__ geom_b,
                                __hip_bfloat16* __restrict__ fusedb) {
    __shared__ float row[MSETS];
    __shared__ float wt[WIN + 1];
    int p = blockIdx.x;
    const float* gw = geom_w + (size_t)p * MSETS;
    for (int j = threadIdx.x; j < MSETS; j += blockDim.x) row[j] = gw[j];
    if (threadIdx.x <= WIN) wt[threadIdx.x] = expf(-(float)threadIdx.x);
    __syncthreads();
    float gb = geom_b[p];
    for (int i = threadIdx.x; i < MSETS; i += blockDim.x) {
        float acc = row[i];
        for (int d = 1; d <= WIN; ++d) {
            float s = 0.0f;
            int lo = i - d, hi = i + d;
            if (lo >= 0) s += row[lo];
            if (hi < MSETS) s += row[hi];
            acc = fmaf(wt[d], s, acc);
        }
        fusedb[(size_t)i * (2 * DPHI) + p] = __float2bfloat16(acc + gb);
    }
}

// ---------------------------------------------------------------- b2 ---------
// b2[n] = rf_b[n] + sum_j rc_b[j] * rf_w[n, 1024+j]   (one block per n)
__global__ __launch_bounds__(256) void b2_kernel(const float* __restrict__ rf_w,
                                                 const float* __restrict__ rf_b,
                                                 const float* __restrict__ rc_b,
                                                 float* __restrict__ b2) {
    int n = blockIdx.x;
    const float* row = rf_w + (size_t)n * (2 * DMODEL) + DMODEL;
    float a = 0.0f;
    for (int j = threadIdx.x; j < DMODEL; j += 256) a = fmaf(rc_b[j], row[j], a);
    for (int o = 32; o > 0; o >>= 1) a += __shfl_down(a, o, 64);
    __shared__ float red[4];
    if ((threadIdx.x & 63) == 0) red[threadIdx.x >> 6] = a;
    __syncthreads();
    if (threadIdx.x == 0) b2[n] = rf_b[n] + red[0] + red[1] + red[2] + red[3];
}

// ------------------------------------------------------ small converters ----
__global__ void cvt_bf16(const float* __restrict__ s, __hip_bfloat16* __restrict__ d, int n4) {
    int i = blockIdx.x * blockDim.x + threadIdx.x;
    if (i >= n4) return;
    float4 v = ((const float4*)s)[i];
    union { __hip_bfloat16 h[4]; ushort4 u; } cv;
    cv.h[0] = __float2bfloat16(v.x);
    cv.h[1] = __float2bfloat16(v.y);
    cv.h[2] = __float2bfloat16(v.z);
    cv.h[3] = __float2bfloat16(v.w);
    ((ushort4*)d)[i] = cv.u;
}

// catA[:, 0:1024] = bf16(set_states)
__global__ void pack_states(const float* __restrict__ st, __hip_bfloat16* __restrict__ catA) {
    int i = blockIdx.x * blockDim.x + threadIdx.x;   // chunk of 4 floats
    if (i >= MSETS * 256) return;
    int n = i >> 8, c4 = i & 255;
    float4 v = *(const float4*)(st + (size_t)i * 4);
    union { __hip_bfloat16 h[4]; ushort4 u; } cv;
    cv.h[0] = __float2bfloat16(v.x);
    cv.h[1] = __float2bfloat16(v.y);
    cv.h[2] = __float2bfloat16(v.z);
    cv.h[3] = __float2bfloat16(v.w);
    *(ushort4*)(catA + (size_t)n * 1152 + c4 * 4) = cv.u;
}

// catB[n] = [ bf16(rf_w[n, 0:1024]) | bf16(W2[n, 0:128]) ]
__global__ void pack_catB(const float* __restrict__ rf_w, const float* __restrict__ W2,
                          __hip_bfloat16* __restrict__ catB) {
    int i = blockIdx.x * blockDim.x + threadIdx.x;   // chunk of 4
    if (i >= DMODEL * 288) return;
    int n = i / 288, c4 = i % 288;
    const float* src = (c4 < 256) ? rf_w + (size_t)n * 2048 + c4 * 4
                                  : W2 + (size_t)n * 128 + (c4 - 256) * 4;
    float4 v = *(const float4*)src;
    union { __hip_bfloat16 h[4]; ushort4 u; } cv;
    cv.h[0] = __float2bfloat16(v.x);
    cv.h[1] = __float2bfloat16(v.y);
    cv.h[2] = __float2bfloat16(v.z);
    cv.h[3] = __float2bfloat16(v.w);
    *(ushort4*)(catB + (size_t)n * 1152 + c4 * 4) = cv.u;
}

// ------------------------------------------------------------ fp32 GEMM ------
// kept only for W2 = rf_wB @ rc_w (small). C[M,N] = A[M,K] @ B[K,N]
__global__ __launch_bounds__(256) void gemm64(const float* __restrict__ A, int lda,
                                              const float* __restrict__ B, int ldb,
                                              float* __restrict__ C, int ldc, int K) {
    __shared__ float As[16][68];
    __shared__ float Bs[16][68];
    const int tid = threadIdx.x;
    const int tx = tid & 15, ty = tid >> 4;
    const int i0 = blockIdx.y * 64, j0 = blockIdx.x * 64;
    const int arow = tid >> 2, akq = (tid & 3) * 4;
    float acc[4][4] = {};
    for (int k0 = 0; k0 < K; k0 += 16) {
        float4 a4 = *(const float4*)(A + (size_t)(i0 + arow) * lda + k0 + akq);
        As[akq + 0][arow] = a4.x;
        As[akq + 1][arow] = a4.y;
        As[akq + 2][arow] = a4.z;
        As[akq + 3][arow] = a4.w;
        int bk = tid >> 4, bj = (tid & 15) * 4;
        float4 b4 = *(const float4*)(B + (size_t)(k0 + bk) * ldb + j0 + bj);
        *(float4*)&Bs[bk][bj] = b4;
        __syncthreads();
#pragma unroll
        for (int kk = 0; kk < 16; ++kk) {
            float4 a = *(const float4*)&As[kk][ty * 4];
            float4 b = *(const float4*)&Bs[kk][tx * 4];
            float av[4] = {a.x, a.y, a.z, a.w};
            float bv[4] = {b.x, b.y, b.z, b.w};
#pragma unroll
            for (int r = 0; r < 4; ++r)
#pragma unroll
                for (int c = 0; c < 4; ++c)
                    acc[r][c] = fmaf(av[r], bv[c], acc[r][c]);
        }
        __syncthreads();
    }
#pragma unroll
    for (int r = 0; r < 4; ++r) {
        int i = i0 + ty * 4 + r;
        *(float4*)(C + (size_t)i * ldc + j0 + tx * 4) =
            make_float4(acc[r][0], acc[r][1], acc[r][2], acc[r][3]);
    }
}

// ------------------------------------------------------- bf16 MFMA GEMM ------
// C[M,N] = A[M,K] @ B[N,K]^T + bias ; 128x128 tile, BK=64, 4 waves (2x2).
// LDS tiles XOR-swizzled: logical (row r, 16B-slot c) at phys slot r*8 + (c^(r&7)).
template<int ACT, bool BF16OUT>
__global__ __launch_bounds__(256) void gemm_mfma(
    const __hip_bfloat16* __restrict__ A, int lda,
    const __hip_bfloat16* __restrict__ B, int ldb,
    void* __restrict__ C, int ldc,
    const float* __restrict__ bias, int K) {
    __shared__ char lds[2 * 128 * 128];       // A: 128x64 bf16 (16KB) + B same
    char* As = lds;
    char* Bs = lds + 128 * 128;

    const int tid = threadIdx.x;
    const int lane = tid & 63;
    const int wave = tid >> 6;
    const int wm = wave >> 1, wn = wave & 1;
    const int l16 = lane & 15, lq = lane >> 4;
    const int i0 = blockIdx.y * 128, j0 = blockIdx.x * 128;

    // staging: thread handles 4 slots (16B each) for A and B per K-tile
    const char* pA[4];
    const char* pB[4];
    unsigned ldsOff[4];
#pragma unroll
    for (int q = 0; q < 4; ++q) {
        int s = q * 256 + tid;
        int r = s >> 3, cl = s & 7;
        pA[q] = (const char*)A + (size_t)(i0 + r) * lda * 2 + cl * 16;
        pB[q] = (const char*)B + (size_t)(j0 + r) * ldb * 2 + cl * 16;
        ldsOff[q] = (unsigned)(r * 8 + (cl ^ (r & 7))) * 16u;
    }

    // fragment LDS offsets (loop-invariant)
    unsigned aoff[4][2], boff[4][2];
#pragma unroll
    for (int m = 0; m < 4; ++m)
#pragma unroll
        for (int kk = 0; kk < 2; ++kk) {
            int ca = kk * 4 + lq;
            int ra = wm * 64 + m * 16 + l16;
            aoff[m][kk] = (unsigned)(ra * 8 + (ca ^ (ra & 7))) * 16u;
            int rb = wn * 64 + m * 16 + l16;
            boff[m][kk] = (unsigned)(rb * 8 + (ca ^ (rb & 7))) * 16u;
        }

    f32x4 acc[4][4] = {};
    uint4 ra[4], rb[4];
    const int nt = K >> 6;
#pragma unroll
    for (int q = 0; q < 4; ++q) {
        ra[q] = *(const uint4*)(pA[q]);
        rb[q] = *(const uint4*)(pB[q]);
    }
    for (int t = 0; t < nt; ++t) {
        __syncthreads();
#pragma unroll
        for (int q = 0; q < 4; ++q) {
            *(uint4*)(As + ldsOff[q]) = ra[q];
            *(uint4*)(Bs + ldsOff[q]) = rb[q];
        }
        __syncthreads();
        if (t + 1 < nt) {
            size_t go = (size_t)(t + 1) * 128;   // 64 elems * 2B
#pragma unroll
            for (int q = 0; q < 4; ++q) {
                ra[q] = *(const uint4*)(pA[q] + go);
                rb[q] = *(const uint4*)(pB[q] + go);
            }
        }
#pragma unroll
        for (int kk = 0; kk < 2; ++kk) {
            bf16x8 af[4], bfv[4];
#pragma unroll
            for (int m = 0; m < 4; ++m) af[m] = *(const bf16x8*)(As + aoff[m][kk]);
#pragma unroll
            for (int n = 0; n < 4; ++n) bfv[n] = *(const bf16x8*)(Bs + boff[n][kk]);
#pragma unroll
            for (int m = 0; m < 4; ++m)
#pragma unroll
                for (int n = 0; n < 4; ++n)
                    acc[m][n] = __builtin_amdgcn_mfma_f32_16x16x32_bf16(
                        af[m], bfv[n], acc[m][n], 0, 0, 0);
        }
    }

    // epilogue: C row = (lane>>4)*4 + reg, col = lane&15  (m89-verified)
#pragma unroll
    for (int n = 0; n < 4; ++n) {
        int col = j0 + wn * 64 + n * 16 + l16;
        float bv = bias ? bias[col] : 0.0f;
#pragma unroll
        for (int m = 0; m < 4; ++m) {
            int row0 = i0 + wm * 64 + m * 16 + lq * 4;
#pragma unroll
            for (int j = 0; j < 4; ++j) {
                float v = acc[m][n][j] + bv;
                if (ACT == 1) v = gelu_exact(v);
                int row = row0 + j;
                if (BF16OUT)
                    ((__hip_bfloat16*)C)[(size_t)row * ldc + col] = __float2bfloat16(v);
                else
                    ((float*)C)[(size_t)row * ldc + col] = v;
            }
        }
    }
}

// ---------------------------------------------------------------- launch -----
extern "C" void kernel_launch(void* const* d_in, const int* in_sizes, int n_in,
                              void* d_out, int out_size, void* d_ws, size_t ws_size,
                              hipStream_t stream) {
    const int*   token_ids   = (const int*)d_in[0];
    const int*   set_indices = (const int*)d_in[1];
    const int*   set_sizes   = (const int*)d_in[2];
    const float* set_pos     = (const float*)d_in[3];
    const float* set_states  = (const float*)d_in[4];
    const float* geom_w      = (const float*)d_in[5];
    const float* geom_b      = (const float*)d_in[6];
    const float* count_w     = (const float*)d_in[7];
    const float* count_b     = (const float*)d_in[8];
    // rc_w = d_in[9]
    const float* rc_w        = (const float*)d_in[9];
    const float* rc_b        = (const float*)d_in[10];
    const float* rf_w        = (const float*)d_in[11];
    const float* rf_b        = (const float*)d_in[12];
    const float* f1_w        = (const float*)d_in[13];
    const float* f1_b        = (const float*)d_in[14];
    const float* f2_w        = (const float*)d_in[15];
    const float* f2_b        = (const float*)d_in[16];

    float* out_phi  = (float*)d_out;                       // [4096,512]
    float* out_desc = out_phi + (size_t)MSETS * DPHI;      // [4096,1024]
    float* out_gb   = out_desc + (size_t)MSETS * DMODEL;   // [4096,4096]

    char* w = (char*)d_ws;
    __hip_bfloat16* catA   = (__hip_bfloat16*)w;                 // [4096,1152]
    __hip_bfloat16* catB   = (__hip_bfloat16*)(w + 9437184);     // [1024,1152]
    __hip_bfloat16* fusedb = (__hip_bfloat16*)(w + 11796480);    // [4096,1024]
    __hip_bfloat16* hb     = (__hip_bfloat16*)(w + 20185088);    // [4096,512]
    __hip_bfloat16* cwb    = (__hip_bfloat16*)(w + 24379392);    // [512,128]
    __hip_bfloat16* f1b    = (__hip_bfloat16*)(w + 24510464);    // [512,1024]
    __hip_bfloat16* f2b    = (__hip_bfloat16*)(w + 25559040);    // [512,512]
    float*          W2     = (float*)(w + 26083328);             // [1024,128] f32
    float*          b2     = (float*)(w + 26607616);             // [1024]

    // independent prep
    counts_kernel<<<MSETS, 256, 0, stream>>>(token_ids, set_indices, set_sizes, catA);
    pack_states<<<(MSETS * 256 + 255) / 256, 256, 0, stream>>>(set_states, catA);
    geom_bias_kernel<<<MSETS, 256, 0, stream>>>(set_pos, out_gb);
    projgeom_kernel<<<DPHI, 256, 0, stream>>>(geom_w, geom_b, fusedb);
    cvt_bf16<<<(DPHI * NBINS / 4 + 255) / 256, 256, 0, stream>>>(count_w, cwb, DPHI * NBINS / 4);
    cvt_bf16<<<(DPHI * 2 * DPHI / 4 + 255) / 256, 256, 0, stream>>>(f1_w, f1b, DPHI * 2 * DPHI / 4);
    cvt_bf16<<<(DPHI * DPHI / 4 + 255) / 256, 256, 0, stream>>>(f2_w, f2b, DPHI * DPHI / 4);

    // fold: W2 = rf_w[:,1024:2048] @ rc_w ; b2 = rf_b + rc_b @ rf_wB^T
    gemm64<<<dim3(NBINS / 64, DMODEL / 64), 256, 0, stream>>>(
        rf_w + DMODEL, 2 * DMODEL, rc_w, NBINS, W2, NBINS, DMODEL);
    b2_kernel<<<DMODEL, 256, 0, stream>>>(rf_w, rf_b, rc_b, b2);
    pack_catB<<<(DMODEL * 288 + 255) / 256, 256, 0, stream>>>(rf_w, W2, catB);

    // proj_counts -> fusedb[:, 512:1024]   (A = counts slice of catA)
    gemm_mfma<0, true><<<dim3(DPHI / 128, MSETS / 128), 256, 0, stream>>>(
        catA + 1024, 1152, cwb, NBINS, fusedb + DPHI, 2 * DPHI, count_b, NBINS);

    // desc_router = catA @ catB^T + b2  (K=1152 concat-fold)
    gemm_mfma<0, false><<<dim3(DMODEL / 128, MSETS / 128), 256, 0, stream>>>(
        catA, 1152, catB, 1152, out_desc, DMODEL, b2, 1152);

    // h = gelu(fusedb @ f1_w^T + f1_b)
    gemm_mfma<1, true><<<dim3(DPHI / 128, MSETS / 128), 256, 0, stream>>>(
        fusedb, 2 * DPHI, f1b, 2 * DPHI, hb, DPHI, f1_b, 2 * DPHI);

    // phi_attn = h @ f2_w^T + f2_b
    gemm_mfma<0, false><<<dim3(DPHI / 128, MSETS / 128), 256, 0, stream>>>(
        hb, DPHI, f2b, DPHI, out_phi, DPHI, f2_b, DPHI);
}

// Round 3
// 170.897 us; speedup vs baseline: 2.7378x; 1.9680x over previous
//
#include <hip/hip_runtime.h>
#include <hip/hip_bf16.h>
#include <cstdint>
#include <cstddef>

#define MSETS 4096
#define SET_SZ 1024
#define NBINS 128
#define DMODEL 1024
#define DPHI 512
#define WIN 48

typedef float f32x4 __attribute__((ext_vector_type(4)));
typedef __bf16 bf16x8 __attribute__((ext_vector_type(8)));
typedef unsigned short u16x8 __attribute__((ext_vector_type(8)));

__device__ inline float gelu_exact(float x) {
    return 0.5f * x * (1.0f + erff(x * 0.70710678118654752f));
}

__device__ inline void gload16(const char* g, char* l) {
    __builtin_amdgcn_global_load_lds(
        (const __attribute__((address_space(1))) unsigned int*)g,
        (__attribute__((address_space(3))) unsigned int*)l,
        16, 0, 0);
}

__device__ inline void cvt4(const float* __restrict__ s, __hip_bfloat16* __restrict__ d) {
    float4 v = *(const float4*)s;
    union { __hip_bfloat16 h[4]; ushort4 u; } cv;
    cv.h[0] = __float2bfloat16(v.x);
    cv.h[1] = __float2bfloat16(v.y);
    cv.h[2] = __float2bfloat16(v.z);
    cv.h[3] = __float2bfloat16(v.w);
    *(ushort4*)d = cv.u;
}

// ------------------------------------------------- counts + pack_states ----
__global__ __launch_bounds__(256) void counts_pack(
    const int* __restrict__ token_ids, const int* __restrict__ set_indices,
    const int* __restrict__ set_sizes, const float* __restrict__ states,
    __hip_bfloat16* __restrict__ catA) {
    __shared__ int hist[NBINS];
    int m = blockIdx.x;
    if (threadIdx.x < NBINS) hist[threadIdx.x] = 0;
    __syncthreads();
    const int* row = set_indices + (size_t)m * SET_SZ;
#pragma unroll
    for (int q = 0; q < 4; ++q) {
        int idx = row[q * 256 + threadIdx.x];
        if (idx >= 0) {
            int tok = token_ids[idx];
            atomicAdd(&hist[((tok & 127) * 39 + 13) & 127], 1);
        }
    }
    // pack set_states row -> catA[m, 0:1024]
    cvt4(states + (size_t)m * DMODEL + threadIdx.x * 4,
         catA + (size_t)m * 1152 + threadIdx.x * 4);
    __syncthreads();
    if (threadIdx.x < NBINS) {
        float denom = fmaxf((float)set_sizes[m], 1.0f);
        catA[(size_t)m * 1152 + 1024 + threadIdx.x] =
            __float2bfloat16((float)hist[threadIdx.x] / denom);
    }
}

// ------------------------------------------------------------- geom_bias ----
__global__ void geom_bias_kernel(const float* __restrict__ pos,
                                 float* __restrict__ out2) {
    __shared__ float sp[MSETS];
    for (int j = threadIdx.x; j < MSETS; j += blockDim.x) sp[j] = pos[j];
    __syncthreads();
    int i = blockIdx.x;
    float pi = sp[i];
    float4* row = (float4*)(out2 + (size_t)i * MSETS);
    const float4* sp4 = (const float4*)sp;
    for (int j4 = threadIdx.x; j4 < MSETS / 4; j4 += blockDim.x) {
        float4 p = sp4[j4];
        float4 v;
        v.x = -fabsf(pi - p.x);
        v.y = -fabsf(pi - p.y);
        v.z = -fabsf(pi - p.z);
        v.w = -fabsf(pi - p.w);
        row[j4] = v;
    }
}

// ---------------------------------------------------- proj_geom (banded) ----
// block = 8 p-rows x 512 i; zero-padded halo; each thread emits 8 bf16 per
// i-row as one 16B store. exp weights fold to literals via unrolled f *= e^-1.
__global__ __launch_bounds__(256) void projgeom_kernel(
    const float* __restrict__ geom_w, const float* __restrict__ geom_b,
    __hip_bfloat16* __restrict__ fusedb) {
    __shared__ float w[8][608];
    __shared__ float gbs[8];
    const int p0 = blockIdx.x * 8;
    const int i0 = blockIdx.y * 512;
    for (int t = threadIdx.x; t < 8 * 608; t += 256) {
        int pr = t / 608, j = t - pr * 608;
        int src = i0 - WIN + j;
        w[pr][j] = (src >= 0 && src < MSETS)
                       ? geom_w[(size_t)(p0 + pr) * MSETS + src] : 0.0f;
    }
    if (threadIdx.x < 8) gbs[threadIdx.x] = geom_b[p0 + threadIdx.x];
    __syncthreads();

    float r0[8], r1[8];
#pragma unroll
    for (int p = 0; p < 8; ++p) {
        const float* wr = &w[p][0];
        const int c0 = WIN + threadIdx.x;
        const int c1 = WIN + 256 + threadIdx.x;
        float a0[4] = {wr[c0], 0.0f, 0.0f, 0.0f};
        float a1[4] = {wr[c1], 0.0f, 0.0f, 0.0f};
        float f = 1.0f;
#pragma unroll
        for (int d = 1; d <= WIN; ++d) {
            f *= 0.36787944117144233f;   // folds to e^-d literals
            a0[d & 3] = fmaf(f, wr[c0 - d] + wr[c0 + d], a0[d & 3]);
            a1[d & 3] = fmaf(f, wr[c1 - d] + wr[c1 + d], a1[d & 3]);
        }
        float gb = gbs[p];
        r0[p] = a0[0] + a0[1] + a0[2] + a0[3] + gb;
        r1[p] = a1[0] + a1[1] + a1[2] + a1[3] + gb;
    }
    union { __hip_bfloat16 h[8]; u16x8 v; } pk0, pk1;
#pragma unroll
    for (int p = 0; p < 8; ++p) {
        pk0.h[p] = __float2bfloat16(r0[p]);
        pk1.h[p] = __float2bfloat16(r1[p]);
    }
    *(u16x8*)(fusedb + (size_t)(i0 + threadIdx.x) * 1024 + p0) = pk0.v;
    *(u16x8*)(fusedb + (size_t)(i0 + 256 + threadIdx.x) * 1024 + p0) = pk1.v;
}

// ---------------------------------------------------------------- b2 ---------
__global__ __launch_bounds__(256) void b2_kernel(const float* __restrict__ rf_w,
                                                 const float* __restrict__ rf_b,
                                                 const float* __restrict__ rc_b,
                                                 float* __restrict__ b2) {
    int n = blockIdx.x;
    const float* row = rf_w + (size_t)n * (2 * DMODEL) + DMODEL;
    float a = 0.0f;
    for (int j = threadIdx.x; j < DMODEL; j += 256) a = fmaf(rc_b[j], row[j], a);
    for (int o = 32; o > 0; o >>= 1) a += __shfl_down(a, o, 64);
    __shared__ float red[4];
    if ((threadIdx.x & 63) == 0) red[threadIdx.x >> 6] = a;
    __syncthreads();
    if (threadIdx.x == 0) b2[n] = rf_b[n] + red[0] + red[1] + red[2] + red[3];
}

// ------------------------------------------------------ weight conversion ----
// one kernel: count_w, f1_w, f2_w, rf_wA->catB[:, :1024], rf_wB->rfBb,
// rc_w -> rc_wT (transposed). All in float4 chunks.
__global__ __launch_bounds__(256) void prep_weights(
    const float* __restrict__ count_w, const float* __restrict__ f1_w,
    const float* __restrict__ f2_w, const float* __restrict__ rf_w,
    const float* __restrict__ rc_w,
    __hip_bfloat16* __restrict__ cwb, __hip_bfloat16* __restrict__ f1b,
    __hip_bfloat16* __restrict__ f2b, __hip_bfloat16* __restrict__ catB,
    __hip_bfloat16* __restrict__ rfBb, __hip_bfloat16* __restrict__ rc_wT) {
    int i = blockIdx.x * 256 + threadIdx.x;
    if (i < 16384) {
        cvt4(count_w + (size_t)i * 4, cwb + (size_t)i * 4);
    } else if (i < 147456) {
        int j = i - 16384;
        cvt4(f1_w + (size_t)j * 4, f1b + (size_t)j * 4);
    } else if (i < 212992) {
        int j = i - 147456;
        cvt4(f2_w + (size_t)j * 4, f2b + (size_t)j * 4);
    } else if (i < 475136) {
        int j = i - 212992;
        int n = j >> 8, c = j & 255;
        cvt4(rf_w + (size_t)n * 2048 + c * 4, catB + (size_t)n * 1152 + c * 4);
    } else if (i < 737280) {
        int j = i - 475136;
        int n = j >> 8, c = j & 255;
        cvt4(rf_w + (size_t)n * 2048 + 1024 + c * 4, rfBb + (size_t)n * 1024 + c * 4);
    } else if (i < 770048) {
        int j = i - 737280;
        int b = j >> 8, jc = (j & 255) * 4;
        union { __hip_bfloat16 h[4]; ushort4 u; } cv;
#pragma unroll
        for (int r = 0; r < 4; ++r)
            cv.h[r] = __float2bfloat16(rc_w[(size_t)(jc + r) * NBINS + b]);
        *(ushort4*)(rc_wT + (size_t)b * 1024 + jc) = cv.u;
    }
}

// ------------------------------------------------------- bf16 MFMA GEMM ------
// C[M,N] = A[M,K] @ B[N,K]^T + bias ; BM=128, BN template, BK=64, 4 waves 2x2.
// Staging: global_load_lds width 16, linear LDS dest, global source column
// pre-XOR-swizzled (rule #21); reads use matching XOR -> conflict-free.
template<int ACT, bool BF16OUT, int BN>
__global__ __launch_bounds__(256) void gemm_mfma(
    const __hip_bfloat16* __restrict__ A, int lda,
    const __hip_bfloat16* __restrict__ B, int ldb,
    void* __restrict__ C, int ldc,
    const float* __restrict__ bias, int K) {
    constexpr int BM = 128;
    constexpr int NF = BN / 32;            // 16-col frags per wave
    constexpr int NBQ = BN * 8 / 256;      // B staging issues per thread
    __shared__ char lds[(BM + BN) * 128];
    char* As = lds;
    char* Bs = lds + BM * 128;

    const int tid = threadIdx.x;
    const int lane = tid & 63;
    const int wave = tid >> 6;
    const int wm = wave >> 1, wn = wave & 1;
    const int l16 = lane & 15, lq = lane >> 4;
    const int i0 = blockIdx.y * BM, j0 = blockIdx.x * BN;

    const char* Ab = (const char*)A;
    const char* Bb = (const char*)B;
    size_t gA[4]; unsigned lA[4];
#pragma unroll
    for (int q = 0; q < 4; ++q) {
        int ws = q * 256 + wave * 64;
        int s = ws + lane;
        int r = s >> 3, pc = s & 7;
        int c = pc ^ (r & 7);
        gA[q] = (size_t)(i0 + r) * lda * 2 + c * 16;
        lA[q] = (unsigned)ws * 16u;
    }
    size_t gB[NBQ]; unsigned lB[NBQ];
#pragma unroll
    for (int q = 0; q < NBQ; ++q) {
        int ws = q * 256 + wave * 64;
        int s = ws + lane;
        int r = s >> 3, pc = s & 7;
        int c = pc ^ (r & 7);
        gB[q] = (size_t)(j0 + r) * ldb * 2 + c * 16;
        lB[q] = (unsigned)ws * 16u;
    }

    unsigned aoff[4][2], boff[NF][2];
#pragma unroll
    for (int kk = 0; kk < 2; ++kk) {
        int ca = kk * 4 + lq;
#pragma unroll
        for (int m = 0; m < 4; ++m) {
            int ra = wm * 64 + m * 16 + l16;
            aoff[m][kk] = (unsigned)(ra * 8 + (ca ^ (ra & 7))) * 16u;
        }
#pragma unroll
        for (int n = 0; n < NF; ++n) {
            int rb = wn * (BN / 2) + n * 16 + l16;
            boff[n][kk] = (unsigned)(rb * 8 + (ca ^ (rb & 7))) * 16u;
        }
    }

    f32x4 acc[4][NF] = {};
    const int nt = K >> 6;
    for (int t = 0; t < nt; ++t) {
        size_t go = (size_t)t * 128;
#pragma unroll
        for (int q = 0; q < 4; ++q) gload16(Ab + gA[q] + go, As + lA[q]);
#pragma unroll
        for (int q = 0; q < NBQ; ++q) gload16(Bb + gB[q] + go, Bs + lB[q]);
        __syncthreads();   // compiler drains vmcnt before barrier
#pragma unroll
        for (int kk = 0; kk < 2; ++kk) {
            bf16x8 af[4], bfv[NF];
#pragma unroll
            for (int m = 0; m < 4; ++m) af[m] = *(const bf16x8*)(As + aoff[m][kk]);
#pragma unroll
            for (int n = 0; n < NF; ++n) bfv[n] = *(const bf16x8*)(Bs + boff[n][kk]);
#pragma unroll
            for (int m = 0; m < 4; ++m)
#pragma unroll
                for (int n = 0; n < NF; ++n)
                    acc[m][n] = __builtin_amdgcn_mfma_f32_16x16x32_bf16(
                        af[m], bfv[n], acc[m][n], 0, 0, 0);
        }
        __syncthreads();
    }

    // C/D: col = lane&15, row = (lane>>4)*4 + reg  (m89-verified)
#pragma unroll
    for (int n = 0; n < NF; ++n) {
        int col = j0 + wn * (BN / 2) + n * 16 + l16;
        float bv = bias ? bias[col] : 0.0f;
#pragma unroll
        for (int m = 0; m < 4; ++m) {
            int row0 = i0 + wm * 64 + m * 16 + lq * 4;
#pragma unroll
            for (int j = 0; j < 4; ++j) {
                float v = acc[m][n][j] + bv;
                if (ACT == 1) v = gelu_exact(v);
                int row = row0 + j;
                if (BF16OUT)
                    ((__hip_bfloat16*)C)[(size_t)row * ldc + col] = __float2bfloat16(v);
                else
                    ((float*)C)[(size_t)row * ldc + col] = v;
            }
        }
    }
}

// ---------------------------------------------------------------- launch -----
extern "C" void kernel_launch(void* const* d_in, const int* in_sizes, int n_in,
                              void* d_out, int out_size, void* d_ws, size_t ws_size,
                              hipStream_t stream) {
    const int*   token_ids   = (const int*)d_in[0];
    const int*   set_indices = (const int*)d_in[1];
    const int*   set_sizes   = (const int*)d_in[2];
    const float* set_pos     = (const float*)d_in[3];
    const float* set_states  = (const float*)d_in[4];
    const float* geom_w      = (const float*)d_in[5];
    const float* geom_b      = (const float*)d_in[6];
    const float* count_w     = (const float*)d_in[7];
    const float* count_b     = (const float*)d_in[8];
    const float* rc_w        = (const float*)d_in[9];
    const float* rc_b        = (const float*)d_in[10];
    const float* rf_w        = (const float*)d_in[11];
    const float* rf_b        = (const float*)d_in[12];
    const float* f1_w        = (const float*)d_in[13];
    const float* f1_b        = (const float*)d_in[14];
    const float* f2_w        = (const float*)d_in[15];
    const float* f2_b        = (const float*)d_in[16];

    float* out_phi  = (float*)d_out;                       // [4096,512]
    float* out_desc = out_phi + (size_t)MSETS * DPHI;      // [4096,1024]
    float* out_gb   = out_desc + (size_t)MSETS * DMODEL;   // [4096,4096]

    char* w = (char*)d_ws;
    __hip_bfloat16* catA   = (__hip_bfloat16*)w;                 // [4096,1152]
    __hip_bfloat16* catB   = (__hip_bfloat16*)(w + 9437184);     // [1024,1152]
    __hip_bfloat16* fusedb = (__hip_bfloat16*)(w + 11796480);    // [4096,1024]
    __hip_bfloat16* hb     = (__hip_bfloat16*)(w + 20185088);    // [4096,512]
    __hip_bfloat16* cwb    = (__hip_bfloat16*)(w + 24379392);    // [512,128]
    __hip_bfloat16* f1b    = (__hip_bfloat16*)(w + 24510464);    // [512,1024]
    __hip_bfloat16* f2b    = (__hip_bfloat16*)(w + 25559040);    // [512,512]
    __hip_bfloat16* rfBb   = (__hip_bfloat16*)(w + 26083328);    // [1024,1024]
    __hip_bfloat16* rc_wT  = (__hip_bfloat16*)(w + 28180480);    // [128,1024]
    float*          b2     = (float*)(w + 28442624);             // [1024]

    prep_weights<<<3008, 256, 0, stream>>>(count_w, f1_w, f2_w, rf_w, rc_w,
                                           cwb, f1b, f2b, catB, rfBb, rc_wT);
    counts_pack<<<MSETS, 256, 0, stream>>>(token_ids, set_indices, set_sizes,
                                           set_states, catA);
    geom_bias_kernel<<<MSETS, 256, 0, stream>>>(set_pos, out_gb);
    projgeom_kernel<<<dim3(DPHI / 8, MSETS / 512), 256, 0, stream>>>(
        geom_w, geom_b, fusedb);
    b2_kernel<<<DMODEL, 256, 0, stream>>>(rf_w, rf_b, rc_b, b2);

    // W2 = rf_wB @ rc_w  -> bf16 straight into catB[:, 1024:1152]
    gemm_mfma<0, true, 128><<<dim3(1, DMODEL / 128), 256, 0, stream>>>(
        rfBb, DMODEL, rc_wT, DMODEL, catB + 1024, 1152, nullptr, DMODEL);

    // proj_counts -> fusedb[:, 512:1024]
    gemm_mfma<0, true, 64><<<dim3(DPHI / 64, MSETS / 128), 256, 0, stream>>>(
        catA + 1024, 1152, cwb, NBINS, fusedb + DPHI, 2 * DPHI, count_b, NBINS);

    // desc_router = catA @ catB^T + b2  (K=1152 concat-fold)
    gemm_mfma<0, false, 128><<<dim3(DMODEL / 128, MSETS / 128), 256, 0, stream>>>(
        catA, 1152, catB, 1152, out_desc, DMODEL, b2, 1152);

    // h = gelu(fusedb @ f1_w^T + f1_b)
    gemm_mfma<1, true, 64><<<dim3(DPHI / 64, MSETS / 128), 256, 0, stream>>>(
        fusedb, 2 * DPHI, f1b, 2 * DPHI, hb, DPHI, f1_b, 2 * DPHI);

    // phi_attn = h @ f2_w^T + f2_b
    gemm_mfma<0, false, 64><<<dim3(DPHI / 64, MSETS / 128), 256, 0, stream>>>(
        hb, DPHI, f2b, DPHI, out_phi, DPHI, f2_b, DPHI);
}

// Round 6
// 157.510 us; speedup vs baseline: 2.9704x; 1.0850x over previous
//
#include <hip/hip_runtime.h>
#include <hip/hip_bf16.h>
#include <cstdint>
#include <cstddef>

#define MSETS 4096
#define SET_SZ 1024
#define NBINS 128
#define DMODEL 1024
#define DPHI 512
#define WIN 48

typedef float f32x4 __attribute__((ext_vector_type(4)));
typedef __bf16 bf16x8 __attribute__((ext_vector_type(8)));
typedef unsigned short u16x8 __attribute__((ext_vector_type(8)));

__device__ inline float gelu_exact(float x) {
    return 0.5f * x * (1.0f + erff(x * 0.70710678118654752f));
}

__device__ inline void gload16(const char* g, char* l) {
    __builtin_amdgcn_global_load_lds(
        (const __attribute__((address_space(1))) unsigned int*)g,
        (__attribute__((address_space(3))) unsigned int*)l,
        16, 0, 0);
}

__device__ inline void cvt4(const float* __restrict__ s, __hip_bfloat16* __restrict__ d) {
    float4 v = *(const float4*)s;
    union { __hip_bfloat16 h[4]; ushort4 u; } cv;
    cv.h[0] = __float2bfloat16(v.x);
    cv.h[1] = __float2bfloat16(v.y);
    cv.h[2] = __float2bfloat16(v.z);
    cv.h[3] = __float2bfloat16(v.w);
    *(ushort4*)d = cv.u;
}

// ------------------------------------------------- counts + pack_states ----
__global__ __launch_bounds__(256) void counts_pack(
    const int* __restrict__ token_ids, const int* __restrict__ set_indices,
    const int* __restrict__ set_sizes, const float* __restrict__ states,
    __hip_bfloat16* __restrict__ catA, __hip_bfloat16* __restrict__ fusedc) {
    __shared__ int hist[NBINS];
    int m = blockIdx.x;
    if (threadIdx.x < NBINS) hist[threadIdx.x] = 0;
    __syncthreads();
    const int* row = set_indices + (size_t)m * SET_SZ;
#pragma unroll
    for (int q = 0; q < 4; ++q) {
        int idx = row[q * 256 + threadIdx.x];
        if (idx >= 0) {
            int tok = token_ids[idx];
            atomicAdd(&hist[((tok & 127) * 39 + 13) & 127], 1);
        }
    }
    cvt4(states + (size_t)m * DMODEL + threadIdx.x * 4,
         catA + (size_t)m * 1152 + threadIdx.x * 4);
    __syncthreads();
    if (threadIdx.x < NBINS) {
        float denom = fmaxf((float)set_sizes[m], 1.0f);
        __hip_bfloat16 c = __float2bfloat16((float)hist[threadIdx.x] / denom);
        catA[(size_t)m * 1152 + 1024 + threadIdx.x] = c;
        fusedc[(size_t)m * 1024 + 512 + threadIdx.x] = c;
    }
}

// ------------------------------------------------------------- geom_bias ----
__global__ void geom_bias_kernel(const float* __restrict__ pos,
                                 float* __restrict__ out2) {
    __shared__ float sp[MSETS];
    for (int j = threadIdx.x; j < MSETS; j += blockDim.x) sp[j] = pos[j];
    __syncthreads();
    int i = blockIdx.x;
    float pi = sp[i];
    float4* row = (float4*)(out2 + (size_t)i * MSETS);
    const float4* sp4 = (const float4*)sp;
    for (int j4 = threadIdx.x; j4 < MSETS / 4; j4 += blockDim.x) {
        float4 p = sp4[j4];
        float4 v;
        v.x = -fabsf(pi - p.x);
        v.y = -fabsf(pi - p.y);
        v.z = -fabsf(pi - p.z);
        v.w = -fabsf(pi - p.w);
        row[j4] = v;
    }
}

// ---------------------------------------------------- proj_geom (banded) ----
__global__ __launch_bounds__(256) void projgeom_kernel(
    const float* __restrict__ geom_w, const float* __restrict__ geom_b,
    __hip_bfloat16* __restrict__ fusedc) {
    __shared__ float w[8][608];
    __shared__ float gbs[8];
    const int p0 = blockIdx.x * 8;
    const int i0 = blockIdx.y * 512;
    for (int t = threadIdx.x; t < 8 * 608; t += 256) {
        int pr = t / 608, j = t - pr * 608;
        int src = i0 - WIN + j;
        w[pr][j] = (src >= 0 && src < MSETS)
                       ? geom_w[(size_t)(p0 + pr) * MSETS + src] : 0.0f;
    }
    if (threadIdx.x < 8) gbs[threadIdx.x] = geom_b[p0 + threadIdx.x];
    __syncthreads();

    float r0[8], r1[8];
#pragma unroll
    for (int p = 0; p < 8; ++p) {
        const float* wr = &w[p][0];
        const int c0 = WIN + threadIdx.x;
        const int c1 = WIN + 256 + threadIdx.x;
        float a0[4] = {wr[c0], 0.0f, 0.0f, 0.0f};
        float a1[4] = {wr[c1], 0.0f, 0.0f, 0.0f};
        float f = 1.0f;
#pragma unroll
        for (int d = 1; d <= WIN; ++d) {
            f *= 0.36787944117144233f;
            a0[d & 3] = fmaf(f, wr[c0 - d] + wr[c0 + d], a0[d & 3]);
            a1[d & 3] = fmaf(f, wr[c1 - d] + wr[c1 + d], a1[d & 3]);
        }
        float gb = gbs[p];
        r0[p] = a0[0] + a0[1] + a0[2] + a0[3] + gb;
        r1[p] = a1[0] + a1[1] + a1[2] + a1[3] + gb;
    }
    union { __hip_bfloat16 h[8]; u16x8 v; } pk0, pk1;
#pragma unroll
    for (int p = 0; p < 8; ++p) {
        pk0.h[p] = __float2bfloat16(r0[p]);
        pk1.h[p] = __float2bfloat16(r1[p]);
    }
    *(u16x8*)(fusedc + (size_t)(i0 + threadIdx.x) * 1024 + p0) = pk0.v;
    *(u16x8*)(fusedc + (size_t)(i0 + 256 + threadIdx.x) * 1024 + p0) = pk1.v;
}

// ---------------------------------------------------------------- b2 ---------
__global__ __launch_bounds__(256) void b2_kernel(const float* __restrict__ rf_w,
                                                 const float* __restrict__ rf_b,
                                                 const float* __restrict__ rc_b,
                                                 float* __restrict__ b2) {
    int n = blockIdx.x;
    const float* row = rf_w + (size_t)n * (2 * DMODEL) + DMODEL;
    float a = 0.0f;
    for (int j = threadIdx.x; j < DMODEL; j += 256) a = fmaf(rc_b[j], row[j], a);
    for (int o = 32; o > 0; o >>= 1) a += __shfl_down(a, o, 64);
    __shared__ float red[4];
    if ((threadIdx.x & 63) == 0) red[threadIdx.x >> 6] = a;
    __syncthreads();
    if (threadIdx.x == 0) b2[n] = rf_b[n] + red[0] + red[1] + red[2] + red[3];
}

// ------------------------------------------------------ weight conversion ----
__global__ __launch_bounds__(256) void prep_weights(
    const float* __restrict__ count_w, const float* __restrict__ f1_w,
    const float* __restrict__ f2_w, const float* __restrict__ rf_w,
    const float* __restrict__ rc_w,
    __hip_bfloat16* __restrict__ cwb, __hip_bfloat16* __restrict__ f1b,
    __hip_bfloat16* __restrict__ f2b, __hip_bfloat16* __restrict__ catB,
    __hip_bfloat16* __restrict__ rfBb, __hip_bfloat16* __restrict__ rc_wT) {
    int i = blockIdx.x * 256 + threadIdx.x;
    if (i < 16384) {
        cvt4(count_w + (size_t)i * 4, cwb + (size_t)i * 4);
    } else if (i < 147456) {
        int j = i - 16384;
        cvt4(f1_w + (size_t)j * 4, f1b + (size_t)j * 4);
    } else if (i < 212992) {
        int j = i - 147456;
        cvt4(f2_w + (size_t)j * 4, f2b + (size_t)j * 4);
    } else if (i < 475136) {
        int j = i - 212992;
        int n = j >> 8, c = j & 255;
        cvt4(rf_w + (size_t)n * 2048 + c * 4, catB + (size_t)n * 1152 + c * 4);
    } else if (i < 737280) {
        int j = i - 475136;
        int n = j >> 8, c = j & 255;
        cvt4(rf_w + (size_t)n * 2048 + 1024 + c * 4, rfBb + (size_t)n * 1024 + c * 4);
    } else if (i < 770048) {
        int j = i - 737280;
        int b = j >> 8, jc = (j & 255) * 4;
        union { __hip_bfloat16 h[4]; ushort4 u; } cv;
#pragma unroll
        for (int r = 0; r < 4; ++r)
            cv.h[r] = __float2bfloat16(rc_w[(size_t)(jc + r) * NBINS + b]);
        *(ushort4*)(rc_wT + (size_t)b * 1024 + jc) = cv.u;
    }
}

// ------------------------------------------------------- bf16 MFMA GEMM ------
// C[M,N] = A[M,K] @ B[N,K]^T + bias ; BM=128, BN template, BK=64, 4 waves 2x2.
// Staging: global_load_lds width 16, linear LDS dest, global source column
// pre-XOR-swizzled (rule #21); reads use matching XOR -> conflict-free.
template<int ACT, bool BF16OUT, int BN>
__global__ __launch_bounds__(256) void gemm_mfma(
    const __hip_bfloat16* __restrict__ A, int lda,
    const __hip_bfloat16* __restrict__ B, int ldb,
    void* __restrict__ C, int ldc,
    const float* __restrict__ bias, int K) {
    constexpr int BM = 128;
    constexpr int NF = BN / 32;            // 16-col frags per wave
    constexpr int NBQ = BN * 8 / 256;      // B staging issues per thread
    __shared__ char lds[(BM + BN) * 128];
    char* As = lds;
    char* Bs = lds + BM * 128;

    const int tid = threadIdx.x;
    const int lane = tid & 63;
    const int wave = tid >> 6;
    const int wm = wave >> 1, wn = wave & 1;
    const int l16 = lane & 15, lq = lane >> 4;
    const int i0 = blockIdx.y * BM, j0 = blockIdx.x * BN;

    const char* Ab = (const char*)A;
    const char* Bb = (const char*)B;
    size_t gA[4]; unsigned lA[4];
#pragma unroll
    for (int q = 0; q < 4; ++q) {
        int ws = q * 256 + wave * 64;
        int s = ws + lane;
        int r = s >> 3, pc = s & 7;
        int c = pc ^ (r & 7);
        gA[q] = (size_t)(i0 + r) * lda * 2 + c * 16;
        lA[q] = (unsigned)ws * 16u;
    }
    size_t gB[NBQ]; unsigned lB[NBQ];
#pragma unroll
    for (int q = 0; q < NBQ; ++q) {
        int ws = q * 256 + wave * 64;
        int s = ws + lane;
        int r = s >> 3, pc = s & 7;
        int c = pc ^ (r & 7);
        gB[q] = (size_t)(j0 + r) * ldb * 2 + c * 16;
        lB[q] = (unsigned)ws * 16u;
    }

    unsigned aoff[4][2], boff[NF][2];
#pragma unroll
    for (int kk = 0; kk < 2; ++kk) {
        int ca = kk * 4 + lq;
#pragma unroll
        for (int m = 0; m < 4; ++m) {
            int ra = wm * 64 + m * 16 + l16;
            aoff[m][kk] = (unsigned)(ra * 8 + (ca ^ (ra & 7))) * 16u;
        }
#pragma unroll
        for (int n = 0; n < NF; ++n) {
            int rb = wn * (BN / 2) + n * 16 + l16;
            boff[n][kk] = (unsigned)(rb * 8 + (ca ^ (rb & 7))) * 16u;
        }
    }

    f32x4 acc[4][NF] = {};
    const int nt = K >> 6;
    for (int t = 0; t < nt; ++t) {
        size_t go = (size_t)t * 128;
#pragma unroll
        for (int q = 0; q < 4; ++q) gload16(Ab + gA[q] + go, As + lA[q]);
#pragma unroll
        for (int q = 0; q < NBQ; ++q) gload16(Bb + gB[q] + go, Bs + lB[q]);
        __syncthreads();
#pragma unroll
        for (int kk = 0; kk < 2; ++kk) {
            bf16x8 af[4], bfv[NF];
#pragma unroll
            for (int m = 0; m < 4; ++m) af[m] = *(const bf16x8*)(As + aoff[m][kk]);
#pragma unroll
            for (int n = 0; n < NF; ++n) bfv[n] = *(const bf16x8*)(Bs + boff[n][kk]);
#pragma unroll
            for (int m = 0; m < 4; ++m)
#pragma unroll
                for (int n = 0; n < NF; ++n)
                    acc[m][n] = __builtin_amdgcn_mfma_f32_16x16x32_bf16(
                        af[m], bfv[n], acc[m][n], 0, 0, 0);
        }
        __syncthreads();
    }

    // C/D: col = lane&15, row = (lane>>4)*4 + reg  (m89-verified)
#pragma unroll
    for (int n = 0; n < NF; ++n) {
        int col = j0 + wn * (BN / 2) + n * 16 + l16;
        float bv = bias ? bias[col] : 0.0f;
#pragma unroll
        for (int m = 0; m < 4; ++m) {
            int row0 = i0 + wm * 64 + m * 16 + lq * 4;
#pragma unroll
            for (int j = 0; j < 4; ++j) {
                float v = acc[m][n][j] + bv;
                if (ACT == 1) v = gelu_exact(v);
                int row = row0 + j;
                if (BF16OUT)
                    ((__hip_bfloat16*)C)[(size_t)row * ldc + col] = __float2bfloat16(v);
                else
                    ((float*)C)[(size_t)row * ldc + col] = v;
            }
        }
    }
}

// ---------------------------------------------------------------- launch -----
extern "C" void kernel_launch(void* const* d_in, const int* in_sizes, int n_in,
                              void* d_out, int out_size, void* d_ws, size_t ws_size,
                              hipStream_t stream) {
    const int*   token_ids   = (const int*)d_in[0];
    const int*   set_indices = (const int*)d_in[1];
    const int*   set_sizes   = (const int*)d_in[2];
    const float* set_pos     = (const float*)d_in[3];
    const float* set_states  = (const float*)d_in[4];
    const float* geom_w      = (const float*)d_in[5];
    const float* geom_b      = (const float*)d_in[6];
    const float* count_w     = (const float*)d_in[7];
    const float* count_b     = (const float*)d_in[8];
    const float* rc_w        = (const float*)d_in[9];
    const float* rc_b        = (const float*)d_in[10];
    const float* rf_w        = (const float*)d_in[11];
    const float* rf_b        = (const float*)d_in[12];
    const float* f1_w        = (const float*)d_in[13];
    const float* f1_b        = (const float*)d_in[14];
    const float* f2_w        = (const float*)d_in[15];
    const float* f2_b        = (const float*)d_in[16];

    float* out_phi  = (float*)d_out;                       // [4096,512]
    float* out_desc = out_phi + (size_t)MSETS * DPHI;      // [4096,1024]
    float* out_gb   = out_desc + (size_t)MSETS * DMODEL;   // [4096,4096]

    char* w = (char*)d_ws;
    __hip_bfloat16* catA   = (__hip_bfloat16*)w;                 // [4096,1152]
    __hip_bfloat16* catB   = (__hip_bfloat16*)(w + 9437184);     // [1024,1152]
    __hip_bfloat16* fusedc = (__hip_bfloat16*)(w + 11796480);    // [4096,1024]
    __hip_bfloat16* hb     = (__hip_bfloat16*)(w + 20185088);    // [4096,512]
    __hip_bfloat16* cwb    = (__hip_bfloat16*)(w + 24379392);    // [512,128]
    __hip_bfloat16* f1b    = (__hip_bfloat16*)(w + 24510464);    // [512,1024]
    __hip_bfloat16* f2b    = (__hip_bfloat16*)(w + 25559040);    // [512,512]
    __hip_bfloat16* rfBb   = (__hip_bfloat16*)(w + 26083328);    // [1024,1024]
    __hip_bfloat16* rc_wT  = (__hip_bfloat16*)(w + 28180480);    // [128,1024]
    float*          b2     = (float*)(w + 28442624);             // [1024]

    prep_weights<<<3008, 256, 0, stream>>>(count_w, f1_w, f2_w, rf_w, rc_w,
                                           cwb, f1b, f2b, catB, rfBb, rc_wT);
    counts_pack<<<MSETS, 256, 0, stream>>>(token_ids, set_indices, set_sizes,
                                           set_states, catA, fusedc);
    geom_bias_kernel<<<MSETS, 256, 0, stream>>>(set_pos, out_gb);
    projgeom_kernel<<<dim3(DPHI / 8, MSETS / 512), 256, 0, stream>>>(
        geom_w, geom_b, fusedc);
    b2_kernel<<<DMODEL, 256, 0, stream>>>(rf_w, rf_b, rc_b, b2);

    // W2 = rf_wB @ rc_w  -> bf16 straight into catB[:, 1024:1152]
    gemm_mfma<0, true, 64><<<dim3(2, DMODEL / 128), 256, 0, stream>>>(
        rfBb, DMODEL, rc_wT, DMODEL, catB + 1024, 1152, nullptr, DMODEL);

    // proj_counts -> fusedc[:, 512:1024]
    gemm_mfma<0, true, 64><<<dim3(DPHI / 64, MSETS / 128), 256, 0, stream>>>(
        catA + 1024, 1152, cwb, NBINS, fusedc + DPHI, 2 * DPHI, count_b, NBINS);

    // desc_router = catA @ catB^T + b2  (K=1152)  [BN=64 -> 512 blocks, 2/CU]
    gemm_mfma<0, false, 64><<<dim3(DMODEL / 64, MSETS / 128), 256, 0, stream>>>(
        catA, 1152, catB, 1152, out_desc, DMODEL, b2, 1152);

    // h = gelu(fusedc @ f1_w^T + f1_b)
    gemm_mfma<1, true, 64><<<dim3(DPHI / 64, MSETS / 128), 256, 0, stream>>>(
        fusedc, 2 * DPHI, f1b, 2 * DPHI, hb, DPHI, f1_b, 2 * DPHI);

    // phi_attn = h @ f2_w^T + f2_b
    gemm_mfma<0, false, 64><<<dim3(DPHI / 64, MSETS / 128), 256, 0, stream>>>(
        hb, DPHI, f2b, DPHI, out_phi, DPHI, f2_b, DPHI);
}